// Round 1
// baseline (20.723 us; speedup 1.0000x reference)
//
#include <hip/hip_runtime.h>
#include <hip/hip_bf16.h>

#define D 64      // hidden dim
#define D2 128    // ff inner dim
#define NV 64     // vocab size
#define NT 4      // num query types
#define NB 256    // batch
#define LL 4096   // seq len
#define KK 8      // memory slots

// ---------------------------------------------------------------------------
// Kernel 1: per-token-value precompute.
// grid = NV blocks (one per vocab id v), 128 threads.
// Computes H[v] = LN(embed[v] + FFN(embed[v])), gH[v] = H[v].gate_w[:64],
// Qrow[v] = H[v] @ q_w + q_b.
// ---------------------------------------------------------------------------
__global__ void __launch_bounds__(128) precompute_kernel(
    const float* __restrict__ embed,
    const float* __restrict__ ff1_w, const float* __restrict__ ff1_b,
    const float* __restrict__ ff2_w, const float* __restrict__ ff2_b,
    const float* __restrict__ ln_g,  const float* __restrict__ ln_b,
    const float* __restrict__ gate_w,
    const float* __restrict__ q_w,   const float* __restrict__ q_b,
    float* __restrict__ Hout, float* __restrict__ gHout, float* __restrict__ Qout)
{
    __shared__ float sE[D];    // embed row, then (embed + ff) in place
    __shared__ float sF[D2];   // relu(ff1) activations
    __shared__ float sH[D];    // LN output

    const int v = blockIdx.x;
    const int tid = threadIdx.x;

    if (tid < D) sE[tid] = embed[v*D + tid];
    __syncthreads();

    // ff1 + relu: thread j computes output j (coalesced ff1_w reads per i)
    {
        float acc = ff1_b[tid];
        #pragma unroll 8
        for (int i = 0; i < D; ++i) acc = fmaf(sE[i], ff1_w[i*D2 + tid], acc);
        sF[tid] = fmaxf(acc, 0.0f);
    }
    __syncthreads();

    // ff2 + residual + LayerNorm — wave 0 only (tid<64 == wave 0 exactly)
    if (tid < D) {
        float acc = ff2_b[tid];
        #pragma unroll 8
        for (int j = 0; j < D2; ++j) acc = fmaf(sF[j], ff2_w[j*D + tid], acc);
        float x = sE[tid] + acc;

        // mean / var over the 64 lanes via butterfly shuffle
        float s = x;
        #pragma unroll
        for (int off = 32; off >= 1; off >>= 1) s += __shfl_xor(s, off, 64);
        float mu = s * (1.0f / D);
        float t  = x - mu;
        float vs = t * t;
        #pragma unroll
        for (int off = 32; off >= 1; off >>= 1) vs += __shfl_xor(vs, off, 64);
        float rs = rsqrtf(vs * (1.0f / D) + 1e-5f);
        float h  = (x - mu) * rs * ln_g[tid] + ln_b[tid];
        sH[tid] = h;
        Hout[v*D + tid] = h;

        // gH[v] = dot(H[v], gate_w[0:64])
        float g = h * gate_w[tid];
        #pragma unroll
        for (int off = 32; off >= 1; off >>= 1) g += __shfl_xor(g, off, 64);
        if (tid == 0) gHout[v] = g;
    }
    __syncthreads();

    // Qrow[v] = H[v] @ q_w + q_b
    if (tid < D) {
        float acc = q_b[tid];
        #pragma unroll 8
        for (int i = 0; i < D; ++i) acc = fmaf(sH[i], q_w[i*D + tid], acc);
        Qout[v*D + tid] = acc;
    }
}

// ---------------------------------------------------------------------------
// Kernel 2: per-batch-row histogram + full finalize.
// grid = NB blocks (one per batch row), 256 threads.
// ---------------------------------------------------------------------------
__global__ void __launch_bounds__(256) batch_kernel(
    const int*   __restrict__ seq,
    const float* __restrict__ Hc, const float* __restrict__ gHc, const float* __restrict__ Qc,
    const float* __restrict__ tp_w, const float* __restrict__ tp_b,
    const float* __restrict__ out_w, const float* __restrict__ out_b,
    float* __restrict__ out)   // logits [0, NB*D), type_dist [NB*D, NB*D+NB*NT)
{
    __shared__ int   cnt[NV];
    __shared__ int   focc[NV];
    __shared__ float sH[NV * D];     // 16 KB: full H table
    __shared__ float sgv[NV];        // gH values (ranking key)
    __shared__ float smean[D];
    __shared__ float std4[NT];
    __shared__ int   order[NV];
    __shared__ int   selv[KK];
    __shared__ int   selc[KK];
    __shared__ float selw[KK];
    __shared__ float ssc[KK];
    __shared__ float sQt[D];
    __shared__ float sread[D];
    __shared__ int   snsel;
    __shared__ int   slast;

    const int b = blockIdx.x;
    const int tid = threadIdx.x;

    if (tid < NV) { cnt[tid] = 0; focc[tid] = 0x7fffffff; sgv[tid] = gHc[tid]; }
    if (tid == 0) slast = seq[(size_t)b * LL + LL - 1];
    __syncthreads();

    // --- histogram of the row's 4096 tokens (coalesced int4 loads) ---
    const int4* s4 = reinterpret_cast<const int4*>(seq + (size_t)b * LL);
    #pragma unroll
    for (int k = 0; k < 4; ++k) {
        int4 x = s4[k * 256 + tid];
        int base = (k * 256 + tid) * 4;
        atomicAdd(&cnt[x.x], 1); atomicMin(&focc[x.x], base);
        atomicAdd(&cnt[x.y], 1); atomicMin(&focc[x.y], base + 1);
        atomicAdd(&cnt[x.z], 1); atomicMin(&focc[x.z], base + 2);
        atomicAdd(&cnt[x.w], 1); atomicMin(&focc[x.w], base + 3);
    }
    // --- stage H table into LDS (overlaps with atomics in flight) ---
    {
        const float4* h4 = reinterpret_cast<const float4*>(Hc);
        float4* sh4 = reinterpret_cast<float4*>(sH);
        #pragma unroll
        for (int k = 0; k < 4; ++k) sh4[k * 256 + tid] = h4[k * 256 + tid];
    }
    __syncthreads();

    // --- mean over L: meanh[d] = sum_v cnt[v]*H[v][d] / L ---
    if (tid < D) {
        float acc = 0.0f;
        #pragma unroll 8
        for (int v = 0; v < NV; ++v) acc = fmaf((float)cnt[v], sH[v*D + tid], acc);
        smean[tid] = acc * (1.0f / LL);
    }
    __syncthreads();

    // --- type logits + softmax -> type_dist output ---
    if (tid < NT) {
        float acc = tp_b[tid];
        #pragma unroll 8
        for (int i = 0; i < D; ++i) acc = fmaf(smean[i], tp_w[i*NT + tid], acc);
        std4[tid] = acc;
    }
    __syncthreads();
    if (tid == 0) {
        float mx = fmaxf(fmaxf(std4[0], std4[1]), fmaxf(std4[2], std4[3]));
        float e0 = expf(std4[0]-mx), e1 = expf(std4[1]-mx);
        float e2 = expf(std4[2]-mx), e3 = expf(std4[3]-mx);
        float inv = 1.0f / (e0 + e1 + e2 + e3);
        std4[0] = e0*inv; std4[1] = e1*inv; std4[2] = e2*inv; std4[3] = e3*inv;
    }
    __syncthreads();
    if (tid < NT) out[NB*D + b*NT + tid] = std4[tid];

    // --- rank present token values by gH desc (tie: first occurrence asc).
    // sigmoid(gH + c_b) is strictly monotone in gH, so ranking by gH matches
    // the reference's gate ranking; the per-row constant and sigmoid drop out.
    if (tid < NV && cnt[tid] > 0) {
        float g = sgv[tid]; int f = focc[tid];
        int r = 0;
        for (int u = 0; u < NV; ++u) {
            if (cnt[u] > 0) {
                float gu = sgv[u];
                if (gu > g || (gu == g && focc[u] < f)) ++r;
            }
        }
        order[r] = tid;
    }
    __syncthreads();

    // --- top-8 multiset: walk ranked values taking min(count, remaining) ---
    if (tid == 0) {
        int taken = 0, idx = 0;
        while (taken < KK) {
            int v = order[idx == 0 ? 0 : idx];  // sequential ranks
            // note: ranks are dense over present values; walk them in order
            v = order[idx];
            int c = cnt[v]; if (c > KK - taken) c = KK - taken;
            selv[idx] = v; selc[idx] = c; taken += c; ++idx;
        }
        snsel = idx;
    }
    if (tid < D) sQt[tid] = Qc[slast*D + tid];   // q vector = Qrow[last token]
    __syncthreads();

    // --- attention scores over distinct selected values ---
    if (tid < snsel) {
        int v = selv[tid];
        float acc = 0.0f;
        #pragma unroll 8
        for (int i = 0; i < D; ++i) acc = fmaf(sH[v*D + i], sQt[i], acc);
        ssc[tid] = acc;
    }
    __syncthreads();
    if (tid == 0) {
        int n = snsel;
        float mx = -1e30f;
        for (int i = 0; i < n; ++i) mx = fmaxf(mx, ssc[i]);
        float e[KK]; float den = 0.0f;
        for (int i = 0; i < n; ++i) { e[i] = (float)selc[i] * expf(ssc[i] - mx); den += e[i]; }
        float inv = 1.0f / den;
        for (int i = 0; i < n; ++i) selw[i] = e[i] * inv;
    }
    __syncthreads();

    // --- read vector, then logits ---
    if (tid < D) {
        float acc = 0.0f;
        int n = snsel;
        for (int s = 0; s < n; ++s) acc = fmaf(selw[s], sH[selv[s]*D + tid], acc);
        sread[tid] = acc;
    }
    __syncthreads();
    if (tid < D) {
        float acc = out_b[tid];
        #pragma unroll 8
        for (int i = 0; i < D; ++i) acc = fmaf(sread[i], out_w[i*D + tid], acc);
        out[(size_t)b*D + tid] = acc;
    }
}

// ---------------------------------------------------------------------------
extern "C" void kernel_launch(void* const* d_in, const int* in_sizes, int n_in,
                              void* d_out, int out_size, void* d_ws, size_t ws_size,
                              hipStream_t stream) {
    const int*   seq    = (const int*)  d_in[0];
    const float* embed  = (const float*)d_in[1];
    const float* ff1_w  = (const float*)d_in[2];
    const float* ff1_b  = (const float*)d_in[3];
    const float* ff2_w  = (const float*)d_in[4];
    const float* ff2_b  = (const float*)d_in[5];
    const float* ln_g   = (const float*)d_in[6];
    const float* ln_b   = (const float*)d_in[7];
    const float* tp_w   = (const float*)d_in[8];
    const float* tp_b   = (const float*)d_in[9];
    // d_in[10] tpr_w, d_in[11] tpr_b, d_in[13] gate_b: not needed —
    // they only shift the gate pre-sigmoid by a per-row constant, which
    // cannot change the top-k ranking (monotone), and tpr feeds only gate.
    const float* gate_w = (const float*)d_in[12];
    const float* q_w    = (const float*)d_in[14];
    const float* q_b    = (const float*)d_in[15];
    const float* out_w  = (const float*)d_in[16];
    const float* out_b  = (const float*)d_in[17];
    float* outp = (float*)d_out;

    float* ws = (float*)d_ws;
    float* H  = ws;               // 4096 floats
    float* gH = ws + 4096;        // 64 floats
    float* Q  = ws + 4096 + 64;   // 4096 floats

    precompute_kernel<<<NV, 128, 0, stream>>>(embed, ff1_w, ff1_b, ff2_w, ff2_b,
                                              ln_g, ln_b, gate_w, q_w, q_b,
                                              H, gH, Q);
    batch_kernel<<<NB, 256, 0, stream>>>(seq, H, gH, Q, tp_w, tp_b,
                                         out_w, out_b, outp);
}

// Round 2
// 17.085 us; speedup vs baseline: 1.2130x; 1.2130x over previous
//
#include <hip/hip_runtime.h>
#include <hip/hip_bf16.h>

#define D 64      // hidden dim
#define D2 128    // ff inner dim
#define NV 64     // vocab size
#define NT 4      // num query types
#define NB 256    // batch
#define LL 4096   // seq len
#define KK 8      // memory slots

// ---------------------------------------------------------------------------
// Kernel 1: per-token-value precompute. grid = NV blocks, 256 threads.
// H[v] = LN(embed[v] + FFN(embed[v])); gH[v] = H[v].gate_w[:64];
// Qrow[v] = H[v] @ q_w + q_b.
// Every dot product is split across 2-4 threads to shorten the latency chain.
// ---------------------------------------------------------------------------
__global__ void __launch_bounds__(256) precompute_kernel(
    const float* __restrict__ embed,
    const float* __restrict__ ff1_w, const float* __restrict__ ff1_b,
    const float* __restrict__ ff2_w, const float* __restrict__ ff2_b,
    const float* __restrict__ ln_g,  const float* __restrict__ ln_b,
    const float* __restrict__ gate_w,
    const float* __restrict__ q_w,   const float* __restrict__ q_b,
    float* __restrict__ Hout, float* __restrict__ gHout, float* __restrict__ Qout)
{
    __shared__ float sE[D];
    __shared__ float sP[256];
    __shared__ float sF[D2];
    __shared__ float sH[D];

    const int v = blockIdx.x;
    const int tid = threadIdx.x;

    if (tid < D) sE[tid] = embed[v*D + tid];
    __syncthreads();

    // ff1 partials: output o = tid&127, half = tid>>7 covers 32 of 64 i's.
    {
        const int o = tid & (D2-1);
        const int half = tid >> 7;
        float acc = 0.0f;
        #pragma unroll
        for (int k = 0; k < 32; ++k) {
            const int i = half*32 + k;
            acc = fmaf(sE[i], ff1_w[i*D2 + o], acc);
        }
        sP[tid] = acc;
    }
    __syncthreads();
    if (tid < D2) sF[tid] = fmaxf(sP[tid] + sP[tid+128] + ff1_b[tid], 0.0f);
    __syncthreads();

    // ff2 partials: output o = tid&63, quarter q = tid>>6 covers 32 of 128 j's.
    {
        const int o = tid & 63, q = tid >> 6;
        float acc = 0.0f;
        #pragma unroll
        for (int k = 0; k < 32; ++k) {
            const int j = q*32 + k;
            acc = fmaf(sF[j], ff2_w[j*D + o], acc);
        }
        sP[tid] = acc;
    }
    __syncthreads();

    // residual + LayerNorm on wave 0 (tid<64 == one full wave)
    if (tid < D) {
        float x = sE[tid] + sP[tid] + sP[tid+64] + sP[tid+128] + sP[tid+192]
                + ff2_b[tid];
        float s = x;
        #pragma unroll
        for (int off = 32; off >= 1; off >>= 1) s += __shfl_xor(s, off, 64);
        const float mu = s * (1.0f / D);
        const float t  = x - mu;
        float vs = t * t;
        #pragma unroll
        for (int off = 32; off >= 1; off >>= 1) vs += __shfl_xor(vs, off, 64);
        const float rs = rsqrtf(vs * (1.0f / D) + 1e-5f);
        const float h  = t * rs * ln_g[tid] + ln_b[tid];
        sH[tid] = h;
        Hout[v*D + tid] = h;
        float g = h * gate_w[tid];
        #pragma unroll
        for (int off = 32; off >= 1; off >>= 1) g += __shfl_xor(g, off, 64);
        if (tid == 0) gHout[v] = g;
    }
    __syncthreads();

    // Qrow partials: output o = tid&63, quarter covers 16 of 64 i's.
    {
        const int o = tid & 63, q = tid >> 6;
        float acc = 0.0f;
        #pragma unroll
        for (int k = 0; k < 16; ++k) {
            const int i = q*16 + k;
            acc = fmaf(sH[i], q_w[i*D + o], acc);
        }
        sP[tid] = acc;
    }
    __syncthreads();
    if (tid < D)
        Qout[v*D + tid] = sP[tid] + sP[tid+64] + sP[tid+128] + sP[tid+192] + q_b[tid];
}

// ---------------------------------------------------------------------------
// Kernel 2: per-batch-row histogram + finalize. grid = NB blocks, 256 threads.
// All global loads issued up front; every phase uses >=64 lanes.
// ---------------------------------------------------------------------------
__global__ void __launch_bounds__(256) batch_kernel(
    const int*   __restrict__ seq,
    const float* __restrict__ Hc, const float* __restrict__ gHc, const float* __restrict__ Qc,
    const float* __restrict__ tp_w, const float* __restrict__ tp_b,
    const float* __restrict__ out_w, const float* __restrict__ out_b,
    float* __restrict__ out)   // logits [0, NB*D), type_dist [NB*D, NB*D+NB*NT)
{
    __shared__ float sH[NV * D];     // 16 KB H table
    __shared__ float sQ[NV * D];     // 16 KB Q table
    __shared__ float sW[D * NV];     // 16 KB out_w
    __shared__ float sP[256];
    __shared__ float stp[D * NT];
    __shared__ float sgv[NV];
    __shared__ float smean[D];
    __shared__ float soub[D];
    __shared__ float stpb[NT];
    __shared__ float sread[D];
    __shared__ float std4[NT];
    __shared__ int   cnt[NV];
    __shared__ int   order[NV];
    __shared__ int   selv[KK], selc[KK];
    __shared__ float selw[KK];
    __shared__ float ssc[KK];
    __shared__ int   snsel;
    __shared__ int   slastS;

    const int b = blockIdx.x;
    const int tid = threadIdx.x;

    // ---- issue ALL global loads up front (one latency wait at the barrier) --
    const int4* s4 = reinterpret_cast<const int4*>(seq + (size_t)b * LL);
    const int4 x0 = s4[tid];
    const int4 x1 = s4[256 + tid];
    const int4 x2 = s4[512 + tid];
    const int4 x3 = s4[768 + tid];

    {
        const float4* h4 = reinterpret_cast<const float4*>(Hc);
        const float4* q4 = reinterpret_cast<const float4*>(Qc);
        const float4* w4 = reinterpret_cast<const float4*>(out_w);
        float4* sh4 = reinterpret_cast<float4*>(sH);
        float4* sq4 = reinterpret_cast<float4*>(sQ);
        float4* sw4 = reinterpret_cast<float4*>(sW);
        #pragma unroll
        for (int k = 0; k < 4; ++k) sh4[k*256 + tid] = h4[k*256 + tid];
        #pragma unroll
        for (int k = 0; k < 4; ++k) sq4[k*256 + tid] = q4[k*256 + tid];
        #pragma unroll
        for (int k = 0; k < 4; ++k) sw4[k*256 + tid] = w4[k*256 + tid];
    }
    if (tid < NV) { cnt[tid] = 0; sgv[tid] = gHc[tid]; soub[tid] = out_b[tid]; }
    if (tid < D*NT) stp[tid] = tp_w[tid];
    if (tid < NT) stpb[tid] = tp_b[tid];
    if (tid == 255) slastS = x3.w;        // seq[b][4095] — already in register
    __syncthreads();

    // ---- histogram (16 LDS atomics / thread; no atomicMin needed) ----------
    atomicAdd(&cnt[x0.x], 1); atomicAdd(&cnt[x0.y], 1);
    atomicAdd(&cnt[x0.z], 1); atomicAdd(&cnt[x0.w], 1);
    atomicAdd(&cnt[x1.x], 1); atomicAdd(&cnt[x1.y], 1);
    atomicAdd(&cnt[x1.z], 1); atomicAdd(&cnt[x1.w], 1);
    atomicAdd(&cnt[x2.x], 1); atomicAdd(&cnt[x2.y], 1);
    atomicAdd(&cnt[x2.z], 1); atomicAdd(&cnt[x2.w], 1);
    atomicAdd(&cnt[x3.x], 1); atomicAdd(&cnt[x3.y], 1);
    atomicAdd(&cnt[x3.z], 1); atomicAdd(&cnt[x3.w], 1);
    __syncthreads();

    // ---- meanh[d] = sum_v cnt[v]*H[v][d] / L  (256 threads, 4-way split) ---
    {
        const int d = tid & 63, g = tid >> 6;
        float acc = 0.0f;
        #pragma unroll
        for (int k = 0; k < 16; ++k) {
            const int v = g*16 + k;
            acc = fmaf((float)cnt[v], sH[v*D + d], acc);
        }
        sP[tid] = acc;
    }
    __syncthreads();
    if (tid < D)
        smean[tid] = (sP[tid] + sP[tid+64] + sP[tid+128] + sP[tid+192]) * (1.0f / LL);
    __syncthreads();

    // ---- type logits: one wave per type, lane i handles term i -------------
    {
        const int t = tid >> 6, i = tid & 63;
        float val = smean[i] * stp[i*NT + t];
        #pragma unroll
        for (int off = 32; off >= 1; off >>= 1) val += __shfl_xor(val, off, 64);
        if (i == 0) std4[t] = val + stpb[t];
    }
    __syncthreads();
    if (tid < NT) {
        const float a0 = std4[0], a1 = std4[1], a2 = std4[2], a3 = std4[3];
        const float mx = fmaxf(fmaxf(a0, a1), fmaxf(a2, a3));
        const float den = expf(a0-mx) + expf(a1-mx) + expf(a2-mx) + expf(a3-mx);
        out[NB*D + b*NT + tid] = expf(std4[tid] - mx) / den;
    }

    // ---- rank present token values by (gH desc, id asc).
    // sigmoid(gH + per-row-const) is strictly monotone in gH, so this matches
    // the reference's gate ranking; tpr/gate_b/sigmoid all drop out. Same-id
    // ties give identical h rows (multiset equal); distinct-id exact-float
    // ties are measure-zero.
    if (tid < NV && cnt[tid] > 0) {
        const float g = sgv[tid];
        int r = 0;
        for (int u = 0; u < NV; ++u) {
            if (cnt[u] > 0) {
                const float gu = sgv[u];
                if (gu > g || (gu == g && u < tid)) ++r;
            }
        }
        order[r] = tid;
    }
    __syncthreads();

    // ---- top-8 multiset walk (serial but <=8 steps) ------------------------
    if (tid == 0) {
        int taken = 0, idx = 0;
        while (taken < KK) {
            const int v = order[idx];
            int c = cnt[v]; if (c > KK - taken) c = KK - taken;
            selv[idx] = v; selc[idx] = c; taken += c; ++idx;
        }
        snsel = idx;
    }
    __syncthreads();

    // ---- attention scores: wave w handles slots w and w+4 ------------------
    {
        const int w = tid >> 6, i = tid & 63;
        const int n = snsel;
        const int sl = slastS;
        #pragma unroll
        for (int s = 0; s < KK; s += 4) {
            const int slot = s + w;
            if (slot < n) {
                float val = sH[selv[slot]*D + i] * sQ[sl*D + i];
                #pragma unroll
                for (int off = 32; off >= 1; off >>= 1) val += __shfl_xor(val, off, 64);
                if (i == 0) ssc[slot] = val;
            }
        }
    }
    __syncthreads();
    if (tid == 0) {
        const int n = snsel;
        float mx = -1e30f;
        for (int i = 0; i < n; ++i) mx = fmaxf(mx, ssc[i]);
        float e[KK]; float den = 0.0f;
        for (int i = 0; i < n; ++i) { e[i] = (float)selc[i] * expf(ssc[i] - mx); den += e[i]; }
        const float inv = 1.0f / den;
        for (int i = 0; i < n; ++i) selw[i] = e[i] * inv;
    }
    __syncthreads();

    // ---- read vector -------------------------------------------------------
    if (tid < D) {
        float acc = 0.0f;
        const int n = snsel;
        for (int s = 0; s < n; ++s) acc = fmaf(selw[s], sH[selv[s]*D + tid], acc);
        sread[tid] = acc;
    }
    __syncthreads();

    // ---- logits = read @ out_w + out_b  (256 threads, 4-way split) ---------
    {
        const int d = tid & 63, g = tid >> 6;
        float acc = 0.0f;
        #pragma unroll
        for (int k = 0; k < 16; ++k) {
            const int i = g*16 + k;
            acc = fmaf(sread[i], sW[i*D + d], acc);
        }
        sP[tid] = acc;
    }
    __syncthreads();
    if (tid < D)
        out[(size_t)b*D + tid] = sP[tid] + sP[tid+64] + sP[tid+128] + sP[tid+192] + soub[tid];
}

// ---------------------------------------------------------------------------
extern "C" void kernel_launch(void* const* d_in, const int* in_sizes, int n_in,
                              void* d_out, int out_size, void* d_ws, size_t ws_size,
                              hipStream_t stream) {
    const int*   seq    = (const int*)  d_in[0];
    const float* embed  = (const float*)d_in[1];
    const float* ff1_w  = (const float*)d_in[2];
    const float* ff1_b  = (const float*)d_in[3];
    const float* ff2_w  = (const float*)d_in[4];
    const float* ff2_b  = (const float*)d_in[5];
    const float* ln_g   = (const float*)d_in[6];
    const float* ln_b   = (const float*)d_in[7];
    const float* tp_w   = (const float*)d_in[8];
    const float* tp_b   = (const float*)d_in[9];
    // d_in[10] tpr_w, d_in[11] tpr_b, d_in[13] gate_b: dead — they only add a
    // per-row constant to the pre-sigmoid gate, which cannot change top-k.
    const float* gate_w = (const float*)d_in[12];
    const float* q_w    = (const float*)d_in[14];
    const float* q_b    = (const float*)d_in[15];
    const float* out_w  = (const float*)d_in[16];
    const float* out_b  = (const float*)d_in[17];
    float* outp = (float*)d_out;

    float* ws = (float*)d_ws;
    float* H  = ws;               // 4096 floats
    float* gH = ws + 4096;        // 64 floats
    float* Q  = ws + 4096 + 64;   // 4096 floats

    precompute_kernel<<<NV, 256, 0, stream>>>(embed, ff1_w, ff1_b, ff2_w, ff2_b,
                                              ln_g, ln_b, gate_w, q_w, q_b,
                                              H, gH, Q);
    batch_kernel<<<NB, 256, 0, stream>>>(seq, H, gH, Q, tp_w, tp_b,
                                         out_w, out_b, outp);
}